// Round 11
// baseline (456.742 us; speedup 1.0000x reference)
//
#include <hip/hip_runtime.h>
#include <float.h>
#include <math.h>

#define LEAK 0.2f
#define EPS 1e-5f

__device__ __forceinline__ float lrelu(float v){ return v > 0.f ? v : LEAK*v; }

// force a wave-uniform float into an SGPR (frees VGPRs; v_fma takes 1 SGPR src)
__device__ __forceinline__ float rfl(float x){
  return __uint_as_float(__builtin_amdgcn_readfirstlane(__float_as_uint(x)));
}

__device__ __forceinline__ void ln_lrelu16(float* h, const float* __restrict__ g, const float* __restrict__ be){
  float mu = 0.f;
#pragma unroll
  for (int o=0;o<16;o++) mu += h[o];
  mu *= 0.0625f;
  float var = 0.f;
#pragma unroll
  for (int o=0;o<16;o++){ float d = h[o]-mu; var += d*d; }
  var *= 0.0625f;
  float rs = 1.0f / sqrtf(var + EPS);
#pragma unroll
  for (int o=0;o<16;o++){ float v = (h[o]-mu)*rs*g[o] + be[o]; h[o] = lrelu(v); }
}

// Stage 1: per-point candidate float4 (x,y,z,|p|^2) + 3->16->16 MLP w/ LN+lrelu.
__global__ __launch_bounds__(256) void prep_kernel(const float* __restrict__ pc,
    const float* __restrict__ W0, const float* __restrict__ b0, const float* __restrict__ g0, const float* __restrict__ be0,
    const float* __restrict__ W1, const float* __restrict__ b1, const float* __restrict__ g1, const float* __restrict__ be1,
    float4* __restrict__ cand, float* __restrict__ feats)
{
  const int p = blockIdx.x*256 + threadIdx.x;      // 0 .. 256*1024-1
  const int b = p >> 10, n = p & 1023;
  const float* base = pc + b*3072;
  const float x = base[n], y = base[1024+n], z = base[2048+n];
  cand[p] = make_float4(x, y, z, x*x + y*y + z*z);
  float h[16];
#pragma unroll
  for (int o=0;o<16;o++) h[o] = b0[o] + x*W0[o] + y*W0[16+o] + z*W0[32+o];
  ln_lrelu16(h, g0, be0);
  float h2[16];
#pragma unroll
  for (int o=0;o<16;o++){
    float s = b1[o];
#pragma unroll
    for (int c=0;c<16;c++) s += h[c]*W1[c*16+o];
    h2[o] = s;
  }
  ln_lrelu16(h2, g1, be1);
  float4* fo = (float4*)(feats + p*16);
  fo[0] = make_float4(h2[0],h2[1],h2[2],h2[3]);
  fo[1] = make_float4(h2[4],h2[5],h2[6],h2[7]);
  fo[2] = make_float4(h2[8],h2[9],h2[10],h2[11]);
  fo[3] = make_float4(h2[12],h2[13],h2[14],h2[15]);
}

// ---- packed top-k keys: ordered-uint(distance) with 10 index bits in the LSBs.
// Sentinel must NOT be 0xFFFFFFFF (decodes to NaN -> kills all compares).
#define KNN_SENT 0xFF7FFC00u   // enc_key(FLT_MAX, 0): finite, larger than any real key
__device__ __forceinline__ unsigned enc_key(float d, int n){
  unsigned u = __float_as_uint(d);
  u ^= (unsigned)(((int)u) >> 31) | 0x80000000u;   // total-order transform
  return (u & ~1023u) | (unsigned)n;
}
__device__ __forceinline__ float dec_key(unsigned k){
  unsigned u = k ^ ((unsigned)(~(((int)k) >> 31)) | 0x80000000u);
  return __uint_as_float(u);
}

// Branchless insert into ASCENDING sorted dk[16]; drops the current max.
// 2 VALU per slot; key >= dk[15] self-rejects (no-op).
__device__ __forceinline__ void ins_sorted(unsigned (&dk)[16], unsigned key){
  unsigned prev = key;
#pragma unroll
  for (int j=0;j<16;j++){
    unsigned cur = dk[j];
    dk[j] = prev < cur ? prev : cur;
    prev  = cur > key ? cur : key;
  }
}

#define CEX(i,jj) { unsigned a_=dk[i], b_=dk[jj]; dk[i]=a_<b_?a_:b_; dk[jj]=a_<b_?b_:a_; }
// Sort an ascending-bitonic 16-seq with the 4-stage bitonic merge network.
__device__ __forceinline__ void bitonic16_sort(unsigned (&dk)[16]){
  CEX(0,8) CEX(1,9) CEX(2,10) CEX(3,11) CEX(4,12) CEX(5,13) CEX(6,14) CEX(7,15)
  CEX(0,4) CEX(1,5) CEX(2,6) CEX(3,7) CEX(8,12) CEX(9,13) CEX(10,14) CEX(11,15)
  CEX(0,2) CEX(1,3) CEX(4,6) CEX(5,7) CEX(8,10) CEX(9,11) CEX(12,14) CEX(13,15)
  CEX(0,1) CEX(2,3) CEX(4,5) CEX(6,7) CEX(8,9) CEX(10,11) CEX(12,13) CEX(14,15)
}

// KNN top-16. SPLIT threads/query, BPB blocks/batch (grid = 256*BPB, batch-minor).
// Candidates staged in LDS (16/8 KB): scan reads are wave-uniform broadcasts,
// trip re-reads hit ~30-50cyc LDS instead of ~200cyc L2 (round-10 stall source).
// Sorted u32-key list in 16 VGPRs; shared flagging threshold per query via LDS
// atomicMin refreshed per 32-candidate sub-chunk; tree merge of SPLIT lists via
// bitonic lower-half + 4-stage sort (skipped at final level).
// CS: stride (in cand float4s) between staged candidates; QSC: query stride in
// STAGED space. waves_per_eu(4) MIN-ONLY: 128-VGPR budget, no spill.
template<int QSC, int CS, int NQ, int SPLIT, int NCAND, int BPB>
__global__ __attribute__((amdgpu_flat_work_group_size(NQ*SPLIT, NQ*SPLIT), amdgpu_waves_per_eu(4)))
void knn_kernel(const float4* __restrict__ cand, int* __restrict__ idx_out)
{
  constexpr int NC = NCAND / SPLIT;                // candidates per thread
  constexpr int MW = (SPLIT-1)*NQ;
  __shared__ float4 sc[NCAND];
  __shared__ unsigned md[16*MW];
  __shared__ unsigned sT[NQ];
  const int b   = blockIdx.x & 255;                // batch
  const int qb  = (blockIdx.x >> 8) * NQ;          // query base within batch
  const int tid = threadIdx.x;
  const int m = tid & (NQ-1), s = tid / NQ;
  const float4* __restrict__ cb = cand + b*1024;
  for (int i = tid; i < NCAND; i += NQ*SPLIT) sc[i] = cb[i*CS];
  if (s == 0) sT[m] = KNN_SENT;
  __syncthreads();                                 // staging + sT init complete

  const float4 qv = sc[(qb+m)*QSC];
  const float qx2=-2.f*qv.x, qy2=-2.f*qv.y, qz2=-2.f*qv.z;
  const int n0 = s*NC;

  unsigned dk[16];
#pragma unroll
  for (int j=0;j<16;j++) dk[j] = KNN_SENT;

  // fill: first 16 candidates of this thread's range, unconditional.
#pragma unroll
  for (int t=0;t<16;t++){
    float4 c = sc[n0+t];
    float d = fmaf(c.x,qx2, fmaf(c.y,qy2, fmaf(c.z,qz2, c.w)));
    ins_sorted(dk, enc_key(d, n0+t));
  }
  atomicMin(&sT[m], dk[15]);

  // masked scan in 32-candidate sub-chunks against the shared-min threshold;
  // wave-max trips with branchless unconditional insert (stale flags self-reject).
  for (int ch=0; ch<NC/32; ch++){
    const int cb0 = n0 + ch*32;
    unsigned shT = sT[m];
    unsigned Tcur = shT < dk[15] ? shT : dk[15];
    float Tf = dec_key(Tcur);
    unsigned msk = 0u;
    if (ch == 0){
#pragma unroll
      for (int t=16;t<32;t++){
        float4 c = sc[cb0+t];
        float d = fmaf(c.x,qx2, fmaf(c.y,qy2, fmaf(c.z,qz2, c.w)));
        if (d < Tf) msk |= (1u<<t);
      }
    } else {
#pragma unroll
      for (int t=0;t<32;t++){
        float4 c = sc[cb0+t];
        float d = fmaf(c.x,qx2, fmaf(c.y,qy2, fmaf(c.z,qz2, c.w)));
        if (d < Tf) msk |= (1u<<t);
      }
    }
    while (msk){
      const int t = __builtin_ctz(msk);
      msk &= msk-1u;
      float4 c = sc[cb0+t];
      float d = fmaf(c.x,qx2, fmaf(c.y,qy2, fmaf(c.z,qz2, c.w)));
      ins_sorted(dk, enc_key(d, cb0+t));
    }
    atomicMin(&sT[m], dk[15]);
  }

  // tree merge: at level `step`, threads with (s & (2step-1))==step donate
  // their (still-sorted) list once (col = s-1); receivers merge via bitonic
  // lower half, re-sorting only if another level follows.
#pragma unroll
  for (int step=1; step<SPLIT; step<<=1){
    if ((s & (2*step-1)) == step){
      const int col = (s-1)*NQ + m;
#pragma unroll
      for (int j=0;j<16;j++) md[j*MW + col] = dk[j];
    }
    __syncthreads();
    if ((s & (2*step-1)) == 0){
      const int col = (s+step-1)*NQ + m;
#pragma unroll
      for (int j=0;j<16;j++){
        unsigned o = md[(15-j)*MW + col];          // bitonic lower half
        dk[j] = o < dk[j] ? o : dk[j];
      }
      if (2*step < SPLIT) bitonic16_sort(dk);      // keep sorted for next level
    }
  }

  if (s == 0){
    int ik[16];
#pragma unroll
    for (int j=0;j<16;j++) ik[j] = (int)(dk[j] & 1023u);
    int4* op = (int4*)(idx_out + (b*(NQ*BPB) + qb + m)*16);
    op[0] = make_int4(ik[0],ik[1],ik[2],ik[3]);
    op[1] = make_int4(ik[4],ik[5],ik[6],ik[7]);
    op[2] = make_int4(ik[8],ik[9],ik[10],ik[11]);
    op[3] = make_int4(ik[12],ik[13],ik[14],ik[15]);
  }
}

// pointconv1 (19->32, maxpool over 16 NN) fused with fs = lrelu(f1 @ Ws + bs).
// o-tile of 2 with W rows pinned in SGPRs: 38+2 wt SGPRs + ~30 args fits the
// ~102-SGPR wave budget (o-tile 4's 80 overflowed it -> the VGPR spill that
// cost 382 MB/dispatch through round 10). VGPR demand ~55: no spill anywhere.
__global__ __attribute__((amdgpu_flat_work_group_size(512,512)))
void feat1_kernel(const float4* __restrict__ cand,
    const float* __restrict__ feats, const int* __restrict__ idx1,
    const float* __restrict__ W, const float* __restrict__ Wb,
    const float* __restrict__ Ws, const float* __restrict__ bs,
    float* __restrict__ fs_out)
{
  __shared__ float sfeat[1024*20];                 // 80 KB, stride 20
  __shared__ float sx[1024], sy[1024], sz[1024];   // 12 KB
  const int b = blockIdx.x, tid = threadIdx.x;
  const float4* fb4 = (const float4*)(feats + b*16384);
  float4* sf4 = (float4*)sfeat;
#pragma unroll
  for (int i=0;i<8;i++){
    int idx = tid + i*512;                         // float4 id 0..4095
    float4 v = fb4[idx];
    sf4[(idx>>2)*5 + (idx&3)] = v;
  }
  const float4* __restrict__ cb = cand + b*1024;
  { float4 c0 = cb[tid], c1 = cb[tid+512];
    sx[tid]=c0.x; sy[tid]=c0.y; sz[tid]=c0.z;
    sx[tid+512]=c1.x; sy[tid+512]=c1.y; sz[tid+512]=c1.z; }
  __syncthreads();

  const int m = tid;                               // 0..511
  const float qx = sx[2*m], qy = sy[2*m], qz = sz[2*m];
  int idxr[16];
  { const int4* ip = (const int4*)(idx1 + (b*512+m)*16);
    int4 a=ip[0], b2=ip[1], c2=ip[2], d2=ip[3];
    idxr[0]=a.x; idxr[1]=a.y; idxr[2]=a.z; idxr[3]=a.w;
    idxr[4]=b2.x; idxr[5]=b2.y; idxr[6]=b2.z; idxr[7]=b2.w;
    idxr[8]=c2.x; idxr[9]=c2.y; idxr[10]=c2.z; idxr[11]=c2.w;
    idxr[12]=d2.x; idxr[13]=d2.y; idxr[14]=d2.z; idxr[15]=d2.w; }

  float fsacc[8] = {0.f,0.f,0.f,0.f,0.f,0.f,0.f,0.f};
#pragma unroll 1
  for (int og=0; og<16; og++){                     // 16 o-tiles of 2
    const int o0 = og*2;
    float wt[19][2];                               // SGPR-resident (wave-uniform)
#pragma unroll
    for (int c=0;c<19;c++){
      float2 t = *(const float2*)(W + c*32 + o0);
      wt[c][0]=rfl(t.x); wt[c][1]=rfl(t.y);
    }
    const float b0v = rfl(Wb[o0]), b1v = rfl(Wb[o0+1]);
    float acc0 = -FLT_MAX, acc1 = -FLT_MAX;
#pragma unroll
    for (int k=0;k<16;k++){
      const int j = idxr[k];
      const float gx = sx[j]-qx, gy = sy[j]-qy, gz = sz[j]-qz;
      float h0 = b0v + gx*wt[0][0] + gy*wt[1][0] + gz*wt[2][0];
      float h1 = b1v + gx*wt[0][1] + gy*wt[1][1] + gz*wt[2][1];
      const float4* gf = (const float4*)(sfeat + j*20);
#pragma unroll
      for (int cc=0;cc<4;cc++){
        float4 f = gf[cc];
        h0 += f.x*wt[3+4*cc][0] + f.y*wt[4+4*cc][0] + f.z*wt[5+4*cc][0] + f.w*wt[6+4*cc][0];
        h1 += f.x*wt[3+4*cc][1] + f.y*wt[4+4*cc][1] + f.z*wt[5+4*cc][1] + f.w*wt[6+4*cc][1];
      }
      acc0 = fmaxf(acc0, lrelu(h0));
      acc1 = fmaxf(acc1, lrelu(h1));
    }
    const float* w0 = Ws + o0*8;
    const float* w1 = Ws + (o0+1)*8;
#pragma unroll
    for (int p=0;p<8;p++) fsacc[p] += acc0*rfl(w0[p]) + acc1*rfl(w1[p]);
  }
  float r[8];
#pragma unroll
  for (int p=0;p<8;p++) r[p] = lrelu(fsacc[p] + bs[p]);
  float4* op = (float4*)(fs_out + (b*512+m)*8);
  op[0] = make_float4(r[0],r[1],r[2],r[3]);
  op[1] = make_float4(r[4],r[5],r[6],r[7]);
}

// pointconv2 (11->128, maxpool over 16 NN) fused with mean over queries and @We+be.
// wt per-lane (og4-dependent slice): demand ~92 VGPR, fits 128 -- no spill.
__global__ __attribute__((amdgpu_flat_work_group_size(512,512)))
void feat2_kernel(const float4* __restrict__ cand,
    const float* __restrict__ fs, const int* __restrict__ idx2,
    const float* __restrict__ Wc, const float* __restrict__ bc,
    const float* __restrict__ We, const float* __restrict__ beF,
    float* __restrict__ out)
{
  __shared__ float sfs[512*12];                    // 24 KB, stride 12
  __shared__ float sx[512], sy[512], sz[512];      // 6 KB
  __shared__ float sred[128];
  const int b = blockIdx.x, tid = threadIdx.x;
  const float4* cb = cand + b*1024;
  { float4 c0 = cb[2*tid];
    sx[tid]=c0.x; sy[tid]=c0.y; sz[tid]=c0.z; }
  { const float4* fsb = (const float4*)(fs + b*4096);
    float4* sfs4 = (float4*)sfs;
#pragma unroll
    for (int i=0;i<2;i++){
      int idx = tid + i*512;                       // float4 id 0..1023
      float4 v = fsb[idx];
      sfs4[(idx>>1)*3 + (idx&1)] = v;
    } }
  if (tid < 128) sred[tid] = 0.f;
  __syncthreads();

  const int m = tid >> 2, og4 = tid & 3;           // 128 queries x 4 o-groups of 32
  const float qx = sx[4*m], qy = sy[4*m], qz = sz[4*m];
  int idxr[16];
  { const int4* ip = (const int4*)(idx2 + (b*128+m)*16);
    int4 a=ip[0], b2=ip[1], c2=ip[2], d2=ip[3];
    idxr[0]=a.x; idxr[1]=a.y; idxr[2]=a.z; idxr[3]=a.w;
    idxr[4]=b2.x; idxr[5]=b2.y; idxr[6]=b2.z; idxr[7]=b2.w;
    idxr[8]=c2.x; idxr[9]=c2.y; idxr[10]=c2.z; idxr[11]=c2.w;
    idxr[12]=d2.x; idxr[13]=d2.y; idxr[14]=d2.z; idxr[15]=d2.w; }

#pragma unroll 1
  for (int og=0; og<8; og++){                      // 8 o-tiles of 4; o0 = og4*32 + og*4
    const int o0 = og4*32 + og*4;
    float wt[11][4];                               // per-lane (og4-dependent slice)
#pragma unroll
    for (int c=0;c<11;c++){
      float4 t = *(const float4*)(Wc + c*128 + o0);
      wt[c][0]=t.x; wt[c][1]=t.y; wt[c][2]=t.z; wt[c][3]=t.w;
    }
    float btv[4];
    { float4 t = *(const float4*)(bc + o0);
      btv[0]=t.x; btv[1]=t.y; btv[2]=t.z; btv[3]=t.w; }
    float acc[4] = {-FLT_MAX,-FLT_MAX,-FLT_MAX,-FLT_MAX};
#pragma unroll
    for (int k=0;k<16;k++){
      const int j = idxr[k];
      const float gx = sx[j]-qx, gy = sy[j]-qy, gz = sz[j]-qz;
      float h[4];
#pragma unroll
      for (int oo=0;oo<4;oo++)
        h[oo] = btv[oo] + gx*wt[0][oo] + gy*wt[1][oo] + gz*wt[2][oo];
      const float4* fp = (const float4*)(sfs + j*12);
#pragma unroll
      for (int cc=0;cc<2;cc++){
        float4 f = fp[cc];
#pragma unroll
        for (int oo=0;oo<4;oo++)
          h[oo] += f.x*wt[3+4*cc][oo] + f.y*wt[4+4*cc][oo] + f.z*wt[5+4*cc][oo] + f.w*wt[6+4*cc][oo];
      }
#pragma unroll
      for (int oo=0;oo<4;oo++) acc[oo] = fmaxf(acc[oo], lrelu(h[oo]));
    }
    // reduce over the 16 m-values in this wave (lane bits 2..5), then one atomic.
#pragma unroll
    for (int oo=0;oo<4;oo++){
      float v = acc[oo];
      v += __shfl_xor(v, 4);
      v += __shfl_xor(v, 8);
      v += __shfl_xor(v, 16);
      v += __shfl_xor(v, 32);
      if ((threadIdx.x & 60) == 0)                 // one lane per (wave, og4)
        atomicAdd(&sred[o0+oo], v);
    }
  }
  __syncthreads();
  if (tid < 256){
    const int o = tid;
    float s = 0.f;
#pragma unroll 8
    for (int c=0;c<128;c++) s += sred[c]*We[c*256+o];
    out[b*256+o] = beF[o] + s*0.0078125f;          // mean over 128 queries
  }
}

extern "C" void kernel_launch(void* const* d_in, const int* in_sizes, int n_in,
                              void* d_out, int out_size, void* d_ws, size_t ws_size,
                              hipStream_t stream) {
  (void)in_sizes; (void)n_in; (void)out_size; (void)ws_size;
  const float* pc   = (const float*)d_in[0];
  const float* W0   = (const float*)d_in[1];
  const float* b0   = (const float*)d_in[2];
  const float* g0   = (const float*)d_in[3];
  const float* be0  = (const float*)d_in[4];
  const float* W1   = (const float*)d_in[5];
  const float* b1   = (const float*)d_in[6];
  const float* g1   = (const float*)d_in[7];
  const float* be1  = (const float*)d_in[8];
  const float* pcW  = (const float*)d_in[9];
  const float* pcb  = (const float*)d_in[10];
  const float* Ws   = (const float*)d_in[11];
  const float* bs   = (const float*)d_in[12];
  const float* Wc   = (const float*)d_in[13];
  const float* bc   = (const float*)d_in[14];
  const float* We   = (const float*)d_in[15];
  const float* beF  = (const float*)d_in[16];

  char* ws = (char*)d_ws;
  float4* cand0 = (float4*)ws;                        // 4 MB
  float*  feats = (float*)(ws + (4u<<20));            // 16 MB
  int*    idx1  = (int*)  (ws + (20u<<20));           // 8 MB
  float*  fsb   = (float*)(ws + (28u<<20));           // 4 MB
  int*    idx2  = (int*)  (ws + (32u<<20));           // 2 MB
  float*  out   = (float*)d_out;

  prep_kernel<<<1024, 256, 0, stream>>>(pc, W0,b0,g0,be0, W1,b1,g1,be1, cand0, feats);
  knn_kernel<2,1,128,4,1024,4><<<1024, 512, 0, stream>>>(cand0, idx1);  // QSC=2, CS=1
  knn_kernel<4,2, 64,8, 512,2><<< 512, 512, 0, stream>>>(cand0, idx2);  // QSC=4, CS=2
  feat1_kernel<<<256, 512, 0, stream>>>(cand0, feats, idx1, pcW, pcb, Ws, bs, fsb);
  feat2_kernel<<<256, 512, 0, stream>>>(cand0, fsb, idx2, Wc, bc, We, beF, out);
}

// Round 12
// 435.237 us; speedup vs baseline: 1.0494x; 1.0494x over previous
//
#include <hip/hip_runtime.h>
#include <float.h>
#include <math.h>

#define LEAK 0.2f
#define EPS 1e-5f

__device__ __forceinline__ float lrelu(float v){ return v > 0.f ? v : LEAK*v; }

__device__ __forceinline__ void ln_lrelu16(float* h, const float* __restrict__ g, const float* __restrict__ be){
  float mu = 0.f;
#pragma unroll
  for (int o=0;o<16;o++) mu += h[o];
  mu *= 0.0625f;
  float var = 0.f;
#pragma unroll
  for (int o=0;o<16;o++){ float d = h[o]-mu; var += d*d; }
  var *= 0.0625f;
  float rs = 1.0f / sqrtf(var + EPS);
#pragma unroll
  for (int o=0;o<16;o++){ float v = (h[o]-mu)*rs*g[o] + be[o]; h[o] = lrelu(v); }
}

// Stage 1: per-point candidate float4 (x,y,z,|p|^2) + 3->16->16 MLP w/ LN+lrelu.
__global__ __launch_bounds__(256) void prep_kernel(const float* __restrict__ pc,
    const float* __restrict__ W0, const float* __restrict__ b0, const float* __restrict__ g0, const float* __restrict__ be0,
    const float* __restrict__ W1, const float* __restrict__ b1, const float* __restrict__ g1, const float* __restrict__ be1,
    float4* __restrict__ cand, float* __restrict__ feats)
{
  const int p = blockIdx.x*256 + threadIdx.x;      // 0 .. 256*1024-1
  const int b = p >> 10, n = p & 1023;
  const float* base = pc + b*3072;
  const float x = base[n], y = base[1024+n], z = base[2048+n];
  cand[p] = make_float4(x, y, z, x*x + y*y + z*z);
  float h[16];
#pragma unroll
  for (int o=0;o<16;o++) h[o] = b0[o] + x*W0[o] + y*W0[16+o] + z*W0[32+o];
  ln_lrelu16(h, g0, be0);
  float h2[16];
#pragma unroll
  for (int o=0;o<16;o++){
    float s = b1[o];
#pragma unroll
    for (int c=0;c<16;c++) s += h[c]*W1[c*16+o];
    h2[o] = s;
  }
  ln_lrelu16(h2, g1, be1);
  float4* fo = (float4*)(feats + p*16);
  fo[0] = make_float4(h2[0],h2[1],h2[2],h2[3]);
  fo[1] = make_float4(h2[4],h2[5],h2[6],h2[7]);
  fo[2] = make_float4(h2[8],h2[9],h2[10],h2[11]);
  fo[3] = make_float4(h2[12],h2[13],h2[14],h2[15]);
}

// ---- packed top-k keys: ordered-uint(distance) with 10 index bits in the LSBs.
// Sentinel must NOT be 0xFFFFFFFF (decodes to NaN -> kills all compares).
#define KNN_SENT 0xFF7FFC00u   // enc_key(FLT_MAX, 0): finite, larger than any real key
__device__ __forceinline__ unsigned enc_key(float d, int n){
  unsigned u = __float_as_uint(d);
  u ^= (unsigned)(((int)u) >> 31) | 0x80000000u;   // total-order transform
  return (u & ~1023u) | (unsigned)n;
}
__device__ __forceinline__ float dec_key(unsigned k){
  unsigned u = k ^ ((unsigned)(~(((int)k) >> 31)) | 0x80000000u);
  return __uint_as_float(u);
}

// Branchless insert into ASCENDING sorted dk[16]; drops the current max.
// 2 VALU per slot; key >= dk[15] self-rejects (no-op).
__device__ __forceinline__ void ins_sorted(unsigned (&dk)[16], unsigned key){
  unsigned prev = key;
#pragma unroll
  for (int j=0;j<16;j++){
    unsigned cur = dk[j];
    dk[j] = prev < cur ? prev : cur;
    prev  = cur > key ? cur : key;
  }
}

#define CEX(i,jj) { unsigned a_=dk[i], b_=dk[jj]; dk[i]=a_<b_?a_:b_; dk[jj]=a_<b_?b_:a_; }
// Sort an ascending-bitonic 16-seq with the 4-stage bitonic merge network.
__device__ __forceinline__ void bitonic16_sort(unsigned (&dk)[16]){
  CEX(0,8) CEX(1,9) CEX(2,10) CEX(3,11) CEX(4,12) CEX(5,13) CEX(6,14) CEX(7,15)
  CEX(0,4) CEX(1,5) CEX(2,6) CEX(3,7) CEX(8,12) CEX(9,13) CEX(10,14) CEX(11,15)
  CEX(0,2) CEX(1,3) CEX(4,6) CEX(5,7) CEX(8,10) CEX(9,11) CEX(12,14) CEX(13,15)
  CEX(0,1) CEX(2,3) CEX(4,5) CEX(6,7) CEX(8,9) CEX(10,11) CEX(12,13) CEX(14,15)
}

// KNN top-16. SPLIT threads/query, BPB blocks/batch (grid = 256*BPB, batch-minor).
// Candidates staged in LDS; sorted u32-key list in 16 VGPRs; shared flagging
// threshold per query via LDS atomicMin refreshed per 32-candidate sub-chunk;
// tree merge via bitonic lower-half + 4-stage sort (skipped at final level).
// ALLOCATOR RULE (measured r8-r11): VGPR budget = 256/waves_per_eu_min.
// waves_per_eu(2) -> 128-VGPR budget; demand ~60 -> no spill, HW still runs 8.
template<int QSC, int CS, int NQ, int SPLIT, int NCAND, int BPB>
__global__ __attribute__((amdgpu_flat_work_group_size(NQ*SPLIT, NQ*SPLIT), amdgpu_waves_per_eu(2)))
void knn_kernel(const float4* __restrict__ cand, int* __restrict__ idx_out)
{
  constexpr int NC = NCAND / SPLIT;                // candidates per thread
  constexpr int MW = (SPLIT-1)*NQ;
  __shared__ float4 sc[NCAND];
  __shared__ unsigned md[16*MW];
  __shared__ unsigned sT[NQ];
  const int b   = blockIdx.x & 255;                // batch
  const int qb  = (blockIdx.x >> 8) * NQ;          // query base within batch
  const int tid = threadIdx.x;
  const int m = tid & (NQ-1), s = tid / NQ;
  const float4* __restrict__ cb = cand + b*1024;
  for (int i = tid; i < NCAND; i += NQ*SPLIT) sc[i] = cb[i*CS];
  if (s == 0) sT[m] = KNN_SENT;
  __syncthreads();                                 // staging + sT init complete

  const float4 qv = sc[(qb+m)*QSC];
  const float qx2=-2.f*qv.x, qy2=-2.f*qv.y, qz2=-2.f*qv.z;
  const int n0 = s*NC;

  unsigned dk[16];
#pragma unroll
  for (int j=0;j<16;j++) dk[j] = KNN_SENT;

  // fill: first 16 candidates of this thread's range, unconditional.
#pragma unroll
  for (int t=0;t<16;t++){
    float4 c = sc[n0+t];
    float d = fmaf(c.x,qx2, fmaf(c.y,qy2, fmaf(c.z,qz2, c.w)));
    ins_sorted(dk, enc_key(d, n0+t));
  }
  atomicMin(&sT[m], dk[15]);

  // masked scan in 32-candidate sub-chunks against the shared-min threshold;
  // wave-max trips with branchless unconditional insert (stale flags self-reject).
  for (int ch=0; ch<NC/32; ch++){
    const int cb0 = n0 + ch*32;
    unsigned shT = sT[m];
    unsigned Tcur = shT < dk[15] ? shT : dk[15];
    float Tf = dec_key(Tcur);
    unsigned msk = 0u;
    if (ch == 0){
#pragma unroll
      for (int t=16;t<32;t++){
        float4 c = sc[cb0+t];
        float d = fmaf(c.x,qx2, fmaf(c.y,qy2, fmaf(c.z,qz2, c.w)));
        if (d < Tf) msk |= (1u<<t);
      }
    } else {
#pragma unroll
      for (int t=0;t<32;t++){
        float4 c = sc[cb0+t];
        float d = fmaf(c.x,qx2, fmaf(c.y,qy2, fmaf(c.z,qz2, c.w)));
        if (d < Tf) msk |= (1u<<t);
      }
    }
    while (msk){
      const int t = __builtin_ctz(msk);
      msk &= msk-1u;
      float4 c = sc[cb0+t];
      float d = fmaf(c.x,qx2, fmaf(c.y,qy2, fmaf(c.z,qz2, c.w)));
      ins_sorted(dk, enc_key(d, cb0+t));
    }
    atomicMin(&sT[m], dk[15]);
  }

  // tree merge: at level `step`, threads with (s & (2step-1))==step donate
  // their (still-sorted) list once (col = s-1); receivers merge via bitonic
  // lower half, re-sorting only if another level follows.
#pragma unroll
  for (int step=1; step<SPLIT; step<<=1){
    if ((s & (2*step-1)) == step){
      const int col = (s-1)*NQ + m;
#pragma unroll
      for (int j=0;j<16;j++) md[j*MW + col] = dk[j];
    }
    __syncthreads();
    if ((s & (2*step-1)) == 0){
      const int col = (s+step-1)*NQ + m;
#pragma unroll
      for (int j=0;j<16;j++){
        unsigned o = md[(15-j)*MW + col];          // bitonic lower half
        dk[j] = o < dk[j] ? o : dk[j];
      }
      if (2*step < SPLIT) bitonic16_sort(dk);      // keep sorted for next level
    }
  }

  if (s == 0){
    int ik[16];
#pragma unroll
    for (int j=0;j<16;j++) ik[j] = (int)(dk[j] & 1023u);
    int4* op = (int4*)(idx_out + (b*(NQ*BPB) + qb + m)*16);
    op[0] = make_int4(ik[0],ik[1],ik[2],ik[3]);
    op[1] = make_int4(ik[4],ik[5],ik[6],ik[7]);
    op[2] = make_int4(ik[8],ik[9],ik[10],ik[11]);
    op[3] = make_int4(ik[12],ik[13],ik[14],ik[15]);
  }
}

// pointconv1 (19->32, maxpool over 16 NN) fused with fs = lrelu(f1 @ Ws + bs).
// ALLOCATOR RULE (measured r7-r11): VGPR budget = 256/waves_per_eu_min, NOT
// 512/waves. waves_per_eu(1) -> 256-VGPR budget; o-tile-4 demand ~150 -> zero
// spill (the 380-520 MB/dispatch scratch traffic of r7-r11 is gone). LDS 92 KB
// caps residency at 1 block/CU = 2 waves/SIMD; 2x~160 <= 512/SIMD pool: the
// bigger VGPR allocation costs no occupancy.
__global__ __attribute__((amdgpu_flat_work_group_size(512,512), amdgpu_waves_per_eu(1)))
void feat1_kernel(const float4* __restrict__ cand,
    const float* __restrict__ feats, const int* __restrict__ idx1,
    const float* __restrict__ W, const float* __restrict__ Wb,
    const float* __restrict__ Ws, const float* __restrict__ bs,
    float* __restrict__ fs_out)
{
  __shared__ float sfeat[1024*20];                 // 80 KB, stride 20
  __shared__ float sx[1024], sy[1024], sz[1024];   // 12 KB
  const int b = blockIdx.x, tid = threadIdx.x;
  const float4* fb4 = (const float4*)(feats + b*16384);
  float4* sf4 = (float4*)sfeat;
#pragma unroll
  for (int i=0;i<8;i++){
    int idx = tid + i*512;                         // float4 id 0..4095
    float4 v = fb4[idx];
    sf4[(idx>>2)*5 + (idx&3)] = v;
  }
  const float4* __restrict__ cb = cand + b*1024;
  { float4 c0 = cb[tid], c1 = cb[tid+512];
    sx[tid]=c0.x; sy[tid]=c0.y; sz[tid]=c0.z;
    sx[tid+512]=c1.x; sy[tid+512]=c1.y; sz[tid+512]=c1.z; }
  __syncthreads();

  const int m = tid;                               // 0..511
  const float qx = sx[2*m], qy = sy[2*m], qz = sz[2*m];
  int idxr[16];
  { const int4* ip = (const int4*)(idx1 + (b*512+m)*16);
    int4 a=ip[0], b2=ip[1], c2=ip[2], d2=ip[3];
    idxr[0]=a.x; idxr[1]=a.y; idxr[2]=a.z; idxr[3]=a.w;
    idxr[4]=b2.x; idxr[5]=b2.y; idxr[6]=b2.z; idxr[7]=b2.w;
    idxr[8]=c2.x; idxr[9]=c2.y; idxr[10]=c2.z; idxr[11]=c2.w;
    idxr[12]=d2.x; idxr[13]=d2.y; idxr[14]=d2.z; idxr[15]=d2.w; }

  float fsacc[8] = {0.f,0.f,0.f,0.f,0.f,0.f,0.f,0.f};
#pragma unroll 1
  for (int og=0; og<8; og++){                      // 8 o-tiles of 4
    const int o0 = og*4;
    float wt[19][4];                               // VGPR-resident, fits 256 budget
#pragma unroll
    for (int c=0;c<19;c++){
      float4 t = *(const float4*)(W + c*32 + o0);
      wt[c][0]=t.x; wt[c][1]=t.y; wt[c][2]=t.z; wt[c][3]=t.w;
    }
    float btv[4];
    { float4 t = *(const float4*)(Wb + o0);
      btv[0]=t.x; btv[1]=t.y; btv[2]=t.z; btv[3]=t.w; }
    float acc[4] = {-FLT_MAX,-FLT_MAX,-FLT_MAX,-FLT_MAX};
#pragma unroll
    for (int k=0;k<16;k++){
      const int j = idxr[k];
      const float gx = sx[j]-qx, gy = sy[j]-qy, gz = sz[j]-qz;
      float h[4];
#pragma unroll
      for (int oo=0;oo<4;oo++)
        h[oo] = btv[oo] + gx*wt[0][oo] + gy*wt[1][oo] + gz*wt[2][oo];
      const float4* gf = (const float4*)(sfeat + j*20);
#pragma unroll
      for (int cc=0;cc<4;cc++){                    // chunked gather: low max-live
        float4 f = gf[cc];
#pragma unroll
        for (int oo=0;oo<4;oo++)
          h[oo] += f.x*wt[3+4*cc][oo] + f.y*wt[4+4*cc][oo] + f.z*wt[5+4*cc][oo] + f.w*wt[6+4*cc][oo];
      }
#pragma unroll
      for (int oo=0;oo<4;oo++) acc[oo] = fmaxf(acc[oo], lrelu(h[oo]));
    }
#pragma unroll
    for (int oo=0;oo<4;oo++){
      const float* wsrow = Ws + (o0+oo)*8;
#pragma unroll
      for (int p=0;p<8;p++) fsacc[p] += acc[oo]*wsrow[p];
    }
  }
  float r[8];
#pragma unroll
  for (int p=0;p<8;p++) r[p] = lrelu(fsacc[p] + bs[p]);
  float4* op = (float4*)(fs_out + (b*512+m)*8);
  op[0] = make_float4(r[0],r[1],r[2],r[3]);
  op[1] = make_float4(r[4],r[5],r[6],r[7]);
}

// pointconv2 (11->128, maxpool over 16 NN) fused with mean over queries and @We+be.
// waves_per_eu(1): 256-VGPR budget; per-lane wt demand ~100 -> no spill.
// LDS 30.5 KB -> residency limited by waves (4 blocks/CU) not registers.
__global__ __attribute__((amdgpu_flat_work_group_size(512,512), amdgpu_waves_per_eu(1)))
void feat2_kernel(const float4* __restrict__ cand,
    const float* __restrict__ fs, const int* __restrict__ idx2,
    const float* __restrict__ Wc, const float* __restrict__ bc,
    const float* __restrict__ We, const float* __restrict__ beF,
    float* __restrict__ out)
{
  __shared__ float sfs[512*12];                    // 24 KB, stride 12
  __shared__ float sx[512], sy[512], sz[512];      // 6 KB
  __shared__ float sred[128];
  const int b = blockIdx.x, tid = threadIdx.x;
  const float4* cb = cand + b*1024;
  { float4 c0 = cb[2*tid];
    sx[tid]=c0.x; sy[tid]=c0.y; sz[tid]=c0.z; }
  { const float4* fsb = (const float4*)(fs + b*4096);
    float4* sfs4 = (float4*)sfs;
#pragma unroll
    for (int i=0;i<2;i++){
      int idx = tid + i*512;                       // float4 id 0..1023
      float4 v = fsb[idx];
      sfs4[(idx>>1)*3 + (idx&1)] = v;
    } }
  if (tid < 128) sred[tid] = 0.f;
  __syncthreads();

  const int m = tid >> 2, og4 = tid & 3;           // 128 queries x 4 o-groups of 32
  const float qx = sx[4*m], qy = sy[4*m], qz = sz[4*m];
  int idxr[16];
  { const int4* ip = (const int4*)(idx2 + (b*128+m)*16);
    int4 a=ip[0], b2=ip[1], c2=ip[2], d2=ip[3];
    idxr[0]=a.x; idxr[1]=a.y; idxr[2]=a.z; idxr[3]=a.w;
    idxr[4]=b2.x; idxr[5]=b2.y; idxr[6]=b2.z; idxr[7]=b2.w;
    idxr[8]=c2.x; idxr[9]=c2.y; idxr[10]=c2.z; idxr[11]=c2.w;
    idxr[12]=d2.x; idxr[13]=d2.y; idxr[14]=d2.z; idxr[15]=d2.w; }

#pragma unroll 1
  for (int og=0; og<8; og++){                      // 8 o-tiles of 4; o0 = og4*32 + og*4
    const int o0 = og4*32 + og*4;
    float wt[11][4];                               // per-lane (og4-dependent slice)
#pragma unroll
    for (int c=0;c<11;c++){
      float4 t = *(const float4*)(Wc + c*128 + o0);
      wt[c][0]=t.x; wt[c][1]=t.y; wt[c][2]=t.z; wt[c][3]=t.w;
    }
    float btv[4];
    { float4 t = *(const float4*)(bc + o0);
      btv[0]=t.x; btv[1]=t.y; btv[2]=t.z; btv[3]=t.w; }
    float acc[4] = {-FLT_MAX,-FLT_MAX,-FLT_MAX,-FLT_MAX};
#pragma unroll
    for (int k=0;k<16;k++){
      const int j = idxr[k];
      const float gx = sx[j]-qx, gy = sy[j]-qy, gz = sz[j]-qz;
      float h[4];
#pragma unroll
      for (int oo=0;oo<4;oo++)
        h[oo] = btv[oo] + gx*wt[0][oo] + gy*wt[1][oo] + gz*wt[2][oo];
      const float4* fp = (const float4*)(sfs + j*12);
#pragma unroll
      for (int cc=0;cc<2;cc++){
        float4 f = fp[cc];
#pragma unroll
        for (int oo=0;oo<4;oo++)
          h[oo] += f.x*wt[3+4*cc][oo] + f.y*wt[4+4*cc][oo] + f.z*wt[5+4*cc][oo] + f.w*wt[6+4*cc][oo];
      }
#pragma unroll
      for (int oo=0;oo<4;oo++) acc[oo] = fmaxf(acc[oo], lrelu(h[oo]));
    }
    // reduce over the 16 m-values in this wave (lane bits 2..5), then one atomic.
#pragma unroll
    for (int oo=0;oo<4;oo++){
      float v = acc[oo];
      v += __shfl_xor(v, 4);
      v += __shfl_xor(v, 8);
      v += __shfl_xor(v, 16);
      v += __shfl_xor(v, 32);
      if ((threadIdx.x & 60) == 0)                 // one lane per (wave, og4)
        atomicAdd(&sred[o0+oo], v);
    }
  }
  __syncthreads();
  if (tid < 256){
    const int o = tid;
    float s = 0.f;
#pragma unroll 8
    for (int c=0;c<128;c++) s += sred[c]*We[c*256+o];
    out[b*256+o] = beF[o] + s*0.0078125f;          // mean over 128 queries
  }
}

extern "C" void kernel_launch(void* const* d_in, const int* in_sizes, int n_in,
                              void* d_out, int out_size, void* d_ws, size_t ws_size,
                              hipStream_t stream) {
  (void)in_sizes; (void)n_in; (void)out_size; (void)ws_size;
  const float* pc   = (const float*)d_in[0];
  const float* W0   = (const float*)d_in[1];
  const float* b0   = (const float*)d_in[2];
  const float* g0   = (const float*)d_in[3];
  const float* be0  = (const float*)d_in[4];
  const float* W1   = (const float*)d_in[5];
  const float* b1   = (const float*)d_in[6];
  const float* g1   = (const float*)d_in[7];
  const float* be1  = (const float*)d_in[8];
  const float* pcW  = (const float*)d_in[9];
  const float* pcb  = (const float*)d_in[10];
  const float* Ws   = (const float*)d_in[11];
  const float* bs   = (const float*)d_in[12];
  const float* Wc   = (const float*)d_in[13];
  const float* bc   = (const float*)d_in[14];
  const float* We   = (const float*)d_in[15];
  const float* beF  = (const float*)d_in[16];

  char* ws = (char*)d_ws;
  float4* cand0 = (float4*)ws;                        // 4 MB
  float*  feats = (float*)(ws + (4u<<20));            // 16 MB
  int*    idx1  = (int*)  (ws + (20u<<20));           // 8 MB
  float*  fsb   = (float*)(ws + (28u<<20));           // 4 MB
  int*    idx2  = (int*)  (ws + (32u<<20));           // 2 MB
  float*  out   = (float*)d_out;

  prep_kernel<<<1024, 256, 0, stream>>>(pc, W0,b0,g0,be0, W1,b1,g1,be1, cand0, feats);
  knn_kernel<2,1,128,4,1024,4><<<1024, 512, 0, stream>>>(cand0, idx1);  // QSC=2, CS=1
  knn_kernel<4,2, 64,8, 512,2><<< 512, 512, 0, stream>>>(cand0, idx2);  // QSC=4, CS=2
  feat1_kernel<<<256, 512, 0, stream>>>(cand0, feats, idx1, pcW, pcb, Ws, bs, fsb);
  feat2_kernel<<<256, 512, 0, stream>>>(cand0, fsb, idx2, Wc, bc, We, beF, out);
}